// Round 7
// baseline (210.619 us; speedup 1.0000x reference)
//
#include <hip/hip_runtime.h>

// Causal attention, fp32 in/out, B=8 S=2048 D=64, NO 1/sqrt(d) scaling.
// R7: R5 structure with 8 waves/block (512 thr) -> 16 waves/CU resident
// (was 8). R5 counters showed ~80% stall exposure per chunk with only
// 2 waves/SIMD; doubling resident waves divides exposed latency ~2x.
// Triangle pairing kept: every block = exactly 17 key-chunks.
// Coop-launch experiment (R6) failed at the 512-block capacity edge —
// reverted to 2 regular dispatches.
// Fragment layouts (verified R2):
//   A[m][k]: m=lane&15, k=quad*8+j | B[k][n]: n=lane&15, k=quad*8+j
//   C/D:     col=lane&15, row=quad*4+reg

#define BATCH 8
#define SEQ 2048
#define DIM 64
#define NEL (BATCH * SEQ * DIM)
#define NWAVE 8

typedef __attribute__((ext_vector_type(8))) short short8;
typedef __attribute__((ext_vector_type(4))) float f32x4;

#define MFMA(a, b, c) __builtin_amdgcn_mfma_f32_16x16x32_bf16(a, b, c, 0, 0, 0)

__device__ __forceinline__ unsigned short f2bf(float x) {
    unsigned u = __float_as_uint(x);
    unsigned r = u + 0x7fffu + ((u >> 16) & 1u);   // RNE
    return (unsigned short)(r >> 16);
}
__device__ __forceinline__ float bf2f(unsigned short h) {
    return __uint_as_float(((unsigned)h) << 16);
}
__device__ __forceinline__ short8 ld8(const unsigned short* p) {
    return *(const short8*)p;
}

__device__ __forceinline__ float dpp_max16(float x) {
    float o;
    o = __int_as_float(__builtin_amdgcn_update_dpp(0, __float_as_int(x), 0xB1, 0xF, 0xF, true));
    x = fmaxf(x, o);
    o = __int_as_float(__builtin_amdgcn_update_dpp(0, __float_as_int(x), 0x4E, 0xF, 0xF, true));
    x = fmaxf(x, o);
    o = __int_as_float(__builtin_amdgcn_update_dpp(0, __float_as_int(x), 0x141, 0xF, 0xF, true));
    x = fmaxf(x, o);
    o = __int_as_float(__builtin_amdgcn_update_dpp(0, __float_as_int(x), 0x140, 0xF, 0xF, true));
    return fmaxf(x, o);
}
__device__ __forceinline__ float dpp_sum16(float x) {
    float o;
    o = __int_as_float(__builtin_amdgcn_update_dpp(0, __float_as_int(x), 0xB1, 0xF, 0xF, true));
    x += o;
    o = __int_as_float(__builtin_amdgcn_update_dpp(0, __float_as_int(x), 0x4E, 0xF, 0xF, true));
    x += o;
    o = __int_as_float(__builtin_amdgcn_update_dpp(0, __float_as_int(x), 0x141, 0xF, 0xF, true));
    x += o;
    o = __int_as_float(__builtin_amdgcn_update_dpp(0, __float_as_int(x), 0x140, 0xF, 0xF, true));
    return x + o;
}

// ---- pre-pass: Q/K hi-lo split convert + V bf16 transpose ----
__global__ __launch_bounds__(256) void prep(
    const float* __restrict__ Q, const float* __restrict__ K,
    const float* __restrict__ V,
    unsigned short* __restrict__ Qh, unsigned short* __restrict__ Ql,
    unsigned short* __restrict__ Kh, unsigned short* __restrict__ Kl,
    unsigned short* __restrict__ Vt)
{
    __shared__ unsigned short sT[64][72];
    const int blk = blockIdx.x;
    const int t = threadIdx.x;

    if (blk < 2048) {
        const int idx = (blk * 256 + t) * 4;
        const float* src; unsigned short *dh, *dl; int off;
        if (idx < NEL) { src = Q; dh = Qh; dl = Ql; off = idx; }
        else           { src = K; dh = Kh; dl = Kl; off = idx - NEL; }
        float4 v = *(const float4*)(src + off);
        ushort4 h, l;
        h.x = f2bf(v.x); l.x = f2bf(v.x - bf2f(h.x));
        h.y = f2bf(v.y); l.y = f2bf(v.y - bf2f(h.y));
        h.z = f2bf(v.z); l.z = f2bf(v.z - bf2f(h.z));
        h.w = f2bf(v.w); l.w = f2bf(v.w - bf2f(h.w));
        *(ushort4*)(dh + off) = h;
        *(ushort4*)(dl + off) = l;
        return;
    }

    const int tile = blk - 2048;
    const int b = tile >> 5;
    const int s0 = (tile & 31) * 64;
    const int srow = t >> 4;
    const int d4   = (t & 15) * 4;
#pragma unroll
    for (int i = 0; i < 4; ++i) {
        const int row = srow + i * 16;
        float4 v = *(const float4*)(V + ((size_t)(b * SEQ + s0 + row)) * DIM + d4);
        sT[d4 + 0][row] = f2bf(v.x);
        sT[d4 + 1][row] = f2bf(v.y);
        sT[d4 + 2][row] = f2bf(v.z);
        sT[d4 + 3][row] = f2bf(v.w);
    }
    __syncthreads();
    const int d_loc = t & 63;
    const int chunk = t >> 6;
    unsigned short* dst = Vt + ((size_t)(b * DIM + d_loc)) * SEQ + s0 + chunk * 16;
    const unsigned short* srcp = &sT[d_loc][chunk * 16];
    *(float4*)(dst)     = *(const float4*)(srcp);
    *(float4*)(dst + 8) = *(const float4*)(srcp + 8);
}

// ---- main: 512 blocks x 512 threads (8 waves), q-tiles {pair, 127-pair} ----
__global__ __launch_bounds__(512, 4) void attn_main(
    const unsigned short* __restrict__ Qh, const unsigned short* __restrict__ Ql,
    const unsigned short* __restrict__ Kh, const unsigned short* __restrict__ Kl,
    const unsigned short* __restrict__ Vt, float* __restrict__ O)
{
    // per-wave union scratch: sP (ushort[16][136]) == sO (float[16][68]) = 4352B
    __shared__ __align__(16) char scratch[NWAVE][4352];
    __shared__ float sMl[NWAVE][16][2];

    const int bid  = blockIdx.x;
    const int b    = bid & (BATCH - 1);
    const int pair = bid >> 3;              // 0..63

    const int t    = threadIdx.x;           // 0..511
    const int w    = t >> 6;                // wave 0..7
    const int lane = t & 63;
    const int quad = lane >> 4;
    const int n16  = lane & 15;
    const int boff = b * SEQ;

    unsigned short* sPw = (unsigned short*)scratch[w];   // [16][136]
    float*          sOw = (float*)scratch[w];            // [16][68]

    for (int half = 0; half < 2; ++half) {
        const int qt = half ? (127 - pair) : pair;
        const int q0 = qt * 16;
        const int q_max = q0 + 15;

        const unsigned short* qp  = Qh + ((size_t)(boff + q0 + n16)) * DIM + quad * 8;
        const unsigned short* qlp = Ql + ((size_t)(boff + q0 + n16)) * DIM + quad * 8;
        short8 qh0 = ld8(qp),  qh1 = ld8(qp + 32);
        short8 ql0 = ld8(qlp), ql1 = ld8(qlp + 32);

        float m0 = -1e30f, m1 = -1e30f, m2 = -1e30f, m3 = -1e30f;
        float l0 = 0.f, l1 = 0.f, l2 = 0.f, l3 = 0.f;
        f32x4 oacc[4];
#pragma unroll
        for (int i = 0; i < 4; ++i) oacc[i] = (f32x4){0.f, 0.f, 0.f, 0.f};

        for (int kb = w * 128; kb <= q_max; kb += NWAVE * 128) {
            const int rem  = q_max - kb;
            const int nsub = min(8, (rem >> 4) + 1);
            const int nchain = (nsub + 1) >> 1;
            f32x4 sacc[8];

            // ---- QK^T: 8 subtiles in pairs (16 loads in flight) ----
#pragma unroll
            for (int gp = 0; gp < 4; ++gp) {
                const int stA = 2 * gp, stB = stA + 1;
                if (stA < nsub) {
                    const size_t krA = (size_t)(boff + kb + stA * 16 + n16) * DIM + quad * 8;
                    short8 khA0 = ld8(Kh + krA), khA1 = ld8(Kh + krA + 32);
                    short8 klA0 = ld8(Kl + krA), klA1 = ld8(Kl + krA + 32);
                    const bool okB = (stB < nsub);
                    const size_t krB = (size_t)(boff + kb + stB * 16 + n16) * DIM + quad * 8;
                    short8 khB0, khB1, klB0, klB1;
                    if (okB) {
                        khB0 = ld8(Kh + krB); khB1 = ld8(Kh + krB + 32);
                        klB0 = ld8(Kl + krB); klB1 = ld8(Kl + krB + 32);
                    }
                    f32x4 accA = (f32x4){0.f, 0.f, 0.f, 0.f};
                    accA = MFMA(qh0, khA0, accA);
                    accA = MFMA(qh1, khA1, accA);
                    accA = MFMA(qh0, klA0, accA);
                    accA = MFMA(qh1, klA1, accA);
                    accA = MFMA(ql0, khA0, accA);
                    accA = MFMA(ql1, khA1, accA);
                    sacc[stA] = accA;
                    if (okB) {
                        f32x4 accB = (f32x4){0.f, 0.f, 0.f, 0.f};
                        accB = MFMA(qh0, khB0, accB);
                        accB = MFMA(qh1, khB1, accB);
                        accB = MFMA(qh0, klB0, accB);
                        accB = MFMA(qh1, klB1, accB);
                        accB = MFMA(ql0, khB0, accB);
                        accB = MFMA(ql1, khB1, accB);
                        sacc[stB] = accB;
                    } else {
                        sacc[stB] = (f32x4){-1e30f, -1e30f, -1e30f, -1e30f};
                    }
                } else {
                    sacc[stA] = (f32x4){-1e30f, -1e30f, -1e30f, -1e30f};
                    sacc[stB] = (f32x4){-1e30f, -1e30f, -1e30f, -1e30f};
                }
            }

            // ---- causal mask: any chunk overlapping any query row ----
            if (kb + 127 > q0) {
#pragma unroll
                for (int st = 0; st < 8; ++st) {
                    if (st < nsub) {
                        const int key = kb + st * 16 + n16;
#pragma unroll
                        for (int r = 0; r < 4; ++r)
                            if (key > q0 + quad * 4 + r) sacc[st][r] = -1e30f;
                    }
                }
            }

            // ---- online softmax over 128 keys (DPP reductions) ----
            float mt0 = sacc[0][0], mt1 = sacc[0][1], mt2 = sacc[0][2], mt3 = sacc[0][3];
#pragma unroll
            for (int st = 1; st < 8; ++st) {
                mt0 = fmaxf(mt0, sacc[st][0]);
                mt1 = fmaxf(mt1, sacc[st][1]);
                mt2 = fmaxf(mt2, sacc[st][2]);
                mt3 = fmaxf(mt3, sacc[st][3]);
            }
            mt0 = dpp_max16(mt0); mt1 = dpp_max16(mt1);
            mt2 = dpp_max16(mt2); mt3 = dpp_max16(mt3);
            const float mn0 = fmaxf(m0, mt0), mn1 = fmaxf(m1, mt1);
            const float mn2 = fmaxf(m2, mt2), mn3 = fmaxf(m3, mt3);
            const float a0 = __expf(m0 - mn0), a1 = __expf(m1 - mn1);
            const float a2 = __expf(m2 - mn2), a3 = __expf(m3 - mn3);
            m0 = mn0; m1 = mn1; m2 = mn2; m3 = mn3;

            float ps0 = 0.f, ps1 = 0.f, ps2 = 0.f, ps3 = 0.f;
            const int stmax = 2 * nchain;
#pragma unroll
            for (int st = 0; st < 8; ++st) {
                if (st < stmax) {
                    float p0 = 0.f, p1 = 0.f, p2 = 0.f, p3 = 0.f;
                    if (st < nsub) {
                        p0 = __expf(sacc[st][0] - mn0);
                        p1 = __expf(sacc[st][1] - mn1);
                        p2 = __expf(sacc[st][2] - mn2);
                        p3 = __expf(sacc[st][3] - mn3);
                        ps0 += p0; ps1 += p1; ps2 += p2; ps3 += p3;
                    }
                    const int col = st * 16 + n16;
                    sPw[(quad * 4 + 0) * 136 + col] = f2bf(p0);
                    sPw[(quad * 4 + 1) * 136 + col] = f2bf(p1);
                    sPw[(quad * 4 + 2) * 136 + col] = f2bf(p2);
                    sPw[(quad * 4 + 3) * 136 + col] = f2bf(p3);
                }
            }
            ps0 = dpp_sum16(ps0); ps1 = dpp_sum16(ps1);
            ps2 = dpp_sum16(ps2); ps3 = dpp_sum16(ps3);
            l0 = l0 * a0 + ps0; l1 = l1 * a1 + ps1;
            l2 = l2 * a2 + ps2; l3 = l3 * a3 + ps3;
#pragma unroll
            for (int nt = 0; nt < 4; ++nt) {
                oacc[nt][0] *= a0; oacc[nt][1] *= a1;
                oacc[nt][2] *= a2; oacc[nt][3] *= a3;
            }

            // ---- PV over valid 32-key chains (same-wave LDS) ----
#pragma unroll
            for (int ch = 0; ch < 4; ++ch) {
                if (ch < nchain) {
                    short8 pa = ld8(&sPw[n16 * 136 + ch * 32 + quad * 8]);
#pragma unroll
                    for (int nt = 0; nt < 4; ++nt) {
                        const size_t vrow =
                            (size_t)(b * DIM + nt * 16 + n16) * SEQ + kb + ch * 32 + quad * 8;
                        short8 vv = ld8(Vt + vrow);
                        oacc[nt] = MFMA(pa, vv, oacc[nt]);
                    }
                }
            }
        }

        // ---- flash-combine the 8 waves' partials (sO overlays sP) ----
#pragma unroll
        for (int nt = 0; nt < 4; ++nt)
#pragma unroll
            for (int r = 0; r < 4; ++r)
                sOw[(quad * 4 + r) * 68 + nt * 16 + n16] = oacc[nt][r];
        if (n16 == 0) {
            sMl[w][quad * 4 + 0][0] = m0; sMl[w][quad * 4 + 0][1] = l0;
            sMl[w][quad * 4 + 1][0] = m1; sMl[w][quad * 4 + 1][1] = l1;
            sMl[w][quad * 4 + 2][0] = m2; sMl[w][quad * 4 + 2][1] = l2;
            sMl[w][quad * 4 + 3][0] = m3; sMl[w][quad * 4 + 3][1] = l3;
        }
        __syncthreads();

        if (t < 256) {
            const int row  = t >> 4;
            const int col4 = (t & 15) * 4;
            float M = -1e30f;
#pragma unroll
            for (int wv = 0; wv < NWAVE; ++wv) M = fmaxf(M, sMl[wv][row][0]);
            float L = 0.f;
            float ox = 0.f, oy = 0.f, oz = 0.f, ow = 0.f;
#pragma unroll
            for (int wv = 0; wv < NWAVE; ++wv) {
                const float ew = __expf(sMl[wv][row][0] - M);
                L += ew * sMl[wv][row][1];
                const float* op = (const float*)scratch[wv] + row * 68 + col4;
                ox += ew * op[0]; oy += ew * op[1]; oz += ew * op[2]; ow += ew * op[3];
            }
            const float inv = 1.0f / L;
            float4 res = make_float4(ox * inv, oy * inv, oz * inv, ow * inv);
            *(float4*)(O + ((size_t)(boff + q0 + row)) * DIM + col4) = res;
        }

        __syncthreads();   // scratch reused as sP by the next half
    }
}

extern "C" void kernel_launch(void* const* d_in, const int* in_sizes, int n_in,
                              void* d_out, int out_size, void* d_ws, size_t ws_size,
                              hipStream_t stream) {
    const float* q = (const float*)d_in[0];
    const float* k = (const float*)d_in[1];
    const float* v = (const float*)d_in[2];
    float* out = (float*)d_out;

    unsigned short* Qh = (unsigned short*)d_ws;
    unsigned short* Ql = Qh + NEL;
    unsigned short* Kh = Ql + NEL;
    unsigned short* Kl = Kh + NEL;
    unsigned short* Vt = Kl + NEL;   // 10 MB total in d_ws

    prep<<<dim3(2048 + 256), dim3(256), 0, stream>>>(q, k, v, Qh, Ql, Kh, Kl, Vt);
    attn_main<<<dim3(512), dim3(512), 0, stream>>>(Qh, Ql, Kh, Kl, Vt, out);
}

// Round 9
// 127.978 us; speedup vs baseline: 1.6457x; 1.6457x over previous
//
#include <hip/hip_runtime.h>

// Causal attention, fp32 in/out, B=8 S=2048 D=64, NO 1/sqrt(d) scaling.
// R9: two dispatches (grid-wide sync abandoned: R6 coop launch failed at
// capacity; R8 manual barrier hung — 512 blocks @ 2/CU has zero slack if
// dispatch isn't perfectly even). attn_main = R7 body with the launch_bounds
// FIXED: (512,2) not (512,4). R7 evidence: 2nd arg acts as min BLOCKS/CU on
// this toolchain — (512,4) forced VGPR=64 -> 370MB scratch spill. (512,2)
// gives the 128-VGPR cap = R5's natural spill-free allocation, with 8 waves/
// block * 2 blocks/CU = 4 waves/SIMD resident (2x R5).
// Triangle pairing: every block = exactly 17 key-chunks (perfect balance).
// Fragment layouts (verified R2):
//   A[m][k]: m=lane&15, k=quad*8+j | B[k][n]: n=lane&15, k=quad*8+j
//   C/D:     col=lane&15, row=quad*4+reg

#define BATCH 8
#define SEQ 2048
#define DIM 64
#define NEL (BATCH * SEQ * DIM)
#define NWAVE 8

typedef __attribute__((ext_vector_type(8))) short short8;
typedef __attribute__((ext_vector_type(4))) float f32x4;

#define MFMA(a, b, c) __builtin_amdgcn_mfma_f32_16x16x32_bf16(a, b, c, 0, 0, 0)

__device__ __forceinline__ unsigned short f2bf(float x) {
    unsigned u = __float_as_uint(x);
    unsigned r = u + 0x7fffu + ((u >> 16) & 1u);   // RNE
    return (unsigned short)(r >> 16);
}
__device__ __forceinline__ float bf2f(unsigned short h) {
    return __uint_as_float(((unsigned)h) << 16);
}
__device__ __forceinline__ short8 ld8(const unsigned short* p) {
    return *(const short8*)p;
}

__device__ __forceinline__ float dpp_max16(float x) {
    float o;
    o = __int_as_float(__builtin_amdgcn_update_dpp(0, __float_as_int(x), 0xB1, 0xF, 0xF, true));
    x = fmaxf(x, o);
    o = __int_as_float(__builtin_amdgcn_update_dpp(0, __float_as_int(x), 0x4E, 0xF, 0xF, true));
    x = fmaxf(x, o);
    o = __int_as_float(__builtin_amdgcn_update_dpp(0, __float_as_int(x), 0x141, 0xF, 0xF, true));
    x = fmaxf(x, o);
    o = __int_as_float(__builtin_amdgcn_update_dpp(0, __float_as_int(x), 0x140, 0xF, 0xF, true));
    return fmaxf(x, o);
}
__device__ __forceinline__ float dpp_sum16(float x) {
    float o;
    o = __int_as_float(__builtin_amdgcn_update_dpp(0, __float_as_int(x), 0xB1, 0xF, 0xF, true));
    x += o;
    o = __int_as_float(__builtin_amdgcn_update_dpp(0, __float_as_int(x), 0x4E, 0xF, 0xF, true));
    x += o;
    o = __int_as_float(__builtin_amdgcn_update_dpp(0, __float_as_int(x), 0x141, 0xF, 0xF, true));
    x += o;
    o = __int_as_float(__builtin_amdgcn_update_dpp(0, __float_as_int(x), 0x140, 0xF, 0xF, true));
    return x + o;
}

// ---- pre-pass: Q/K hi-lo split convert + V bf16 transpose ----
__global__ __launch_bounds__(256) void prep(
    const float* __restrict__ Q, const float* __restrict__ K,
    const float* __restrict__ V,
    unsigned short* __restrict__ Qh, unsigned short* __restrict__ Ql,
    unsigned short* __restrict__ Kh, unsigned short* __restrict__ Kl,
    unsigned short* __restrict__ Vt)
{
    __shared__ unsigned short sT[64][72];
    const int blk = blockIdx.x;
    const int t = threadIdx.x;

    if (blk < 2048) {
        const int idx = (blk * 256 + t) * 4;
        const float* src; unsigned short *dh, *dl; int off;
        if (idx < NEL) { src = Q; dh = Qh; dl = Ql; off = idx; }
        else           { src = K; dh = Kh; dl = Kl; off = idx - NEL; }
        float4 v = *(const float4*)(src + off);
        ushort4 h, l;
        h.x = f2bf(v.x); l.x = f2bf(v.x - bf2f(h.x));
        h.y = f2bf(v.y); l.y = f2bf(v.y - bf2f(h.y));
        h.z = f2bf(v.z); l.z = f2bf(v.z - bf2f(h.z));
        h.w = f2bf(v.w); l.w = f2bf(v.w - bf2f(h.w));
        *(ushort4*)(dh + off) = h;
        *(ushort4*)(dl + off) = l;
        return;
    }

    const int tile = blk - 2048;
    const int b = tile >> 5;
    const int s0 = (tile & 31) * 64;
    const int srow = t >> 4;
    const int d4   = (t & 15) * 4;
#pragma unroll
    for (int i = 0; i < 4; ++i) {
        const int row = srow + i * 16;
        float4 v = *(const float4*)(V + ((size_t)(b * SEQ + s0 + row)) * DIM + d4);
        sT[d4 + 0][row] = f2bf(v.x);
        sT[d4 + 1][row] = f2bf(v.y);
        sT[d4 + 2][row] = f2bf(v.z);
        sT[d4 + 3][row] = f2bf(v.w);
    }
    __syncthreads();
    const int d_loc = t & 63;
    const int chunk = t >> 6;
    unsigned short* dst = Vt + ((size_t)(b * DIM + d_loc)) * SEQ + s0 + chunk * 16;
    const unsigned short* srcp = &sT[d_loc][chunk * 16];
    *(float4*)(dst)     = *(const float4*)(srcp);
    *(float4*)(dst + 8) = *(const float4*)(srcp + 8);
}

// ---- main: 512 blocks x 512 threads (8 waves), q-tiles {pair, 127-pair} ----
__global__ __launch_bounds__(512, 2) void attn_main(
    const unsigned short* __restrict__ Qh, const unsigned short* __restrict__ Ql,
    const unsigned short* __restrict__ Kh, const unsigned short* __restrict__ Kl,
    const unsigned short* __restrict__ Vt, float* __restrict__ O)
{
    // per-wave union scratch: sP (ushort[16][136]) == sO (float[16][68]) = 4352B
    __shared__ __align__(16) char scratch[NWAVE][4352];
    __shared__ float sMl[NWAVE][16][2];

    const int bid  = blockIdx.x;
    const int b    = bid & (BATCH - 1);
    const int pair = bid >> 3;              // 0..63

    const int t    = threadIdx.x;           // 0..511
    const int w    = t >> 6;                // wave 0..7
    const int lane = t & 63;
    const int quad = lane >> 4;
    const int n16  = lane & 15;
    const int boff = b * SEQ;

    unsigned short* sPw = (unsigned short*)scratch[w];   // [16][136]
    float*          sOw = (float*)scratch[w];            // [16][68]

    for (int half = 0; half < 2; ++half) {
        const int qt = half ? (127 - pair) : pair;
        const int q0 = qt * 16;
        const int q_max = q0 + 15;

        const unsigned short* qp  = Qh + ((size_t)(boff + q0 + n16)) * DIM + quad * 8;
        const unsigned short* qlp = Ql + ((size_t)(boff + q0 + n16)) * DIM + quad * 8;
        short8 qh0 = ld8(qp),  qh1 = ld8(qp + 32);
        short8 ql0 = ld8(qlp), ql1 = ld8(qlp + 32);

        float m0 = -1e30f, m1 = -1e30f, m2 = -1e30f, m3 = -1e30f;
        float l0 = 0.f, l1 = 0.f, l2 = 0.f, l3 = 0.f;
        f32x4 oacc[4];
#pragma unroll
        for (int i = 0; i < 4; ++i) oacc[i] = (f32x4){0.f, 0.f, 0.f, 0.f};

        for (int kb = w * 128; kb <= q_max; kb += NWAVE * 128) {
            const int rem  = q_max - kb;
            const int nsub = min(8, (rem >> 4) + 1);
            const int nchain = (nsub + 1) >> 1;
            f32x4 sacc[8];

            // ---- QK^T: 8 subtiles in pairs (16 loads in flight) ----
#pragma unroll
            for (int gp = 0; gp < 4; ++gp) {
                const int stA = 2 * gp, stB = stA + 1;
                if (stA < nsub) {
                    const size_t krA = (size_t)(boff + kb + stA * 16 + n16) * DIM + quad * 8;
                    short8 khA0 = ld8(Kh + krA), khA1 = ld8(Kh + krA + 32);
                    short8 klA0 = ld8(Kl + krA), klA1 = ld8(Kl + krA + 32);
                    const bool okB = (stB < nsub);
                    const size_t krB = (size_t)(boff + kb + stB * 16 + n16) * DIM + quad * 8;
                    short8 khB0, khB1, klB0, klB1;
                    if (okB) {
                        khB0 = ld8(Kh + krB); khB1 = ld8(Kh + krB + 32);
                        klB0 = ld8(Kl + krB); klB1 = ld8(Kl + krB + 32);
                    }
                    f32x4 accA = (f32x4){0.f, 0.f, 0.f, 0.f};
                    accA = MFMA(qh0, khA0, accA);
                    accA = MFMA(qh1, khA1, accA);
                    accA = MFMA(qh0, klA0, accA);
                    accA = MFMA(qh1, klA1, accA);
                    accA = MFMA(ql0, khA0, accA);
                    accA = MFMA(ql1, khA1, accA);
                    sacc[stA] = accA;
                    if (okB) {
                        f32x4 accB = (f32x4){0.f, 0.f, 0.f, 0.f};
                        accB = MFMA(qh0, khB0, accB);
                        accB = MFMA(qh1, khB1, accB);
                        accB = MFMA(qh0, klB0, accB);
                        accB = MFMA(qh1, klB1, accB);
                        accB = MFMA(ql0, khB0, accB);
                        accB = MFMA(ql1, khB1, accB);
                        sacc[stB] = accB;
                    } else {
                        sacc[stB] = (f32x4){-1e30f, -1e30f, -1e30f, -1e30f};
                    }
                } else {
                    sacc[stA] = (f32x4){-1e30f, -1e30f, -1e30f, -1e30f};
                    sacc[stB] = (f32x4){-1e30f, -1e30f, -1e30f, -1e30f};
                }
            }

            // ---- causal mask: any chunk overlapping any query row ----
            if (kb + 127 > q0) {
#pragma unroll
                for (int st = 0; st < 8; ++st) {
                    if (st < nsub) {
                        const int key = kb + st * 16 + n16;
#pragma unroll
                        for (int r = 0; r < 4; ++r)
                            if (key > q0 + quad * 4 + r) sacc[st][r] = -1e30f;
                    }
                }
            }

            // ---- online softmax over 128 keys (DPP reductions) ----
            float mt0 = sacc[0][0], mt1 = sacc[0][1], mt2 = sacc[0][2], mt3 = sacc[0][3];
#pragma unroll
            for (int st = 1; st < 8; ++st) {
                mt0 = fmaxf(mt0, sacc[st][0]);
                mt1 = fmaxf(mt1, sacc[st][1]);
                mt2 = fmaxf(mt2, sacc[st][2]);
                mt3 = fmaxf(mt3, sacc[st][3]);
            }
            mt0 = dpp_max16(mt0); mt1 = dpp_max16(mt1);
            mt2 = dpp_max16(mt2); mt3 = dpp_max16(mt3);
            const float mn0 = fmaxf(m0, mt0), mn1 = fmaxf(m1, mt1);
            const float mn2 = fmaxf(m2, mt2), mn3 = fmaxf(m3, mt3);
            const float a0 = __expf(m0 - mn0), a1 = __expf(m1 - mn1);
            const float a2 = __expf(m2 - mn2), a3 = __expf(m3 - mn3);
            m0 = mn0; m1 = mn1; m2 = mn2; m3 = mn3;

            float ps0 = 0.f, ps1 = 0.f, ps2 = 0.f, ps3 = 0.f;
            const int stmax = 2 * nchain;
#pragma unroll
            for (int st = 0; st < 8; ++st) {
                if (st < stmax) {
                    float p0 = 0.f, p1 = 0.f, p2 = 0.f, p3 = 0.f;
                    if (st < nsub) {
                        p0 = __expf(sacc[st][0] - mn0);
                        p1 = __expf(sacc[st][1] - mn1);
                        p2 = __expf(sacc[st][2] - mn2);
                        p3 = __expf(sacc[st][3] - mn3);
                        ps0 += p0; ps1 += p1; ps2 += p2; ps3 += p3;
                    }
                    const int col = st * 16 + n16;
                    sPw[(quad * 4 + 0) * 136 + col] = f2bf(p0);
                    sPw[(quad * 4 + 1) * 136 + col] = f2bf(p1);
                    sPw[(quad * 4 + 2) * 136 + col] = f2bf(p2);
                    sPw[(quad * 4 + 3) * 136 + col] = f2bf(p3);
                }
            }
            ps0 = dpp_sum16(ps0); ps1 = dpp_sum16(ps1);
            ps2 = dpp_sum16(ps2); ps3 = dpp_sum16(ps3);
            l0 = l0 * a0 + ps0; l1 = l1 * a1 + ps1;
            l2 = l2 * a2 + ps2; l3 = l3 * a3 + ps3;
#pragma unroll
            for (int nt = 0; nt < 4; ++nt) {
                oacc[nt][0] *= a0; oacc[nt][1] *= a1;
                oacc[nt][2] *= a2; oacc[nt][3] *= a3;
            }

            // ---- PV over valid 32-key chains (same-wave LDS) ----
#pragma unroll
            for (int ch = 0; ch < 4; ++ch) {
                if (ch < nchain) {
                    short8 pa = ld8(&sPw[n16 * 136 + ch * 32 + quad * 8]);
#pragma unroll
                    for (int nt = 0; nt < 4; ++nt) {
                        const size_t vrow =
                            (size_t)(b * DIM + nt * 16 + n16) * SEQ + kb + ch * 32 + quad * 8;
                        short8 vv = ld8(Vt + vrow);
                        oacc[nt] = MFMA(pa, vv, oacc[nt]);
                    }
                }
            }
        }

        // ---- flash-combine the 8 waves' partials (sO overlays sP) ----
#pragma unroll
        for (int nt = 0; nt < 4; ++nt)
#pragma unroll
            for (int r = 0; r < 4; ++r)
                sOw[(quad * 4 + r) * 68 + nt * 16 + n16] = oacc[nt][r];
        if (n16 == 0) {
            sMl[w][quad * 4 + 0][0] = m0; sMl[w][quad * 4 + 0][1] = l0;
            sMl[w][quad * 4 + 1][0] = m1; sMl[w][quad * 4 + 1][1] = l1;
            sMl[w][quad * 4 + 2][0] = m2; sMl[w][quad * 4 + 2][1] = l2;
            sMl[w][quad * 4 + 3][0] = m3; sMl[w][quad * 4 + 3][1] = l3;
        }
        __syncthreads();

        if (t < 256) {
            const int row  = t >> 4;
            const int col4 = (t & 15) * 4;
            float M = -1e30f;
#pragma unroll
            for (int wv = 0; wv < NWAVE; ++wv) M = fmaxf(M, sMl[wv][row][0]);
            float L = 0.f;
            float ox = 0.f, oy = 0.f, oz = 0.f, ow = 0.f;
#pragma unroll
            for (int wv = 0; wv < NWAVE; ++wv) {
                const float ew = __expf(sMl[wv][row][0] - M);
                L += ew * sMl[wv][row][1];
                const float* op = (const float*)scratch[wv] + row * 68 + col4;
                ox += ew * op[0]; oy += ew * op[1]; oz += ew * op[2]; ow += ew * op[3];
            }
            const float inv = 1.0f / L;
            float4 res = make_float4(ox * inv, oy * inv, oz * inv, ow * inv);
            *(float4*)(O + ((size_t)(boff + q0 + row)) * DIM + col4) = res;
        }

        __syncthreads();   // scratch reused as sP by the next half
    }
}

extern "C" void kernel_launch(void* const* d_in, const int* in_sizes, int n_in,
                              void* d_out, int out_size, void* d_ws, size_t ws_size,
                              hipStream_t stream) {
    const float* q = (const float*)d_in[0];
    const float* k = (const float*)d_in[1];
    const float* v = (const float*)d_in[2];
    float* out = (float*)d_out;

    unsigned short* Qh = (unsigned short*)d_ws;
    unsigned short* Ql = Qh + NEL;
    unsigned short* Kh = Ql + NEL;
    unsigned short* Kl = Kh + NEL;
    unsigned short* Vt = Kl + NEL;   // 10 MB total in d_ws

    prep<<<dim3(2048 + 256), dim3(256), 0, stream>>>(q, k, v, Qh, Ql, Kh, Kl, Vt);
    attn_main<<<dim3(512), dim3(512), 0, stream>>>(Qh, Ql, Kh, Kl, Vt, out);
}

// Round 10
// 112.462 us; speedup vs baseline: 1.8728x; 1.1380x over previous
//
#include <hip/hip_runtime.h>

// Causal attention, fp32 in/out, B=8 S=2048 D=64, NO 1/sqrt(d) scaling.
// R10 = R5 (fastest: 54.8us) with ONE change: V stored fragment-major.
// Plateau diagnosis (R2/R4/R5/R9 all ~55-62us regardless of occupancy/
// balance): PV's Vt loads were address-divergent — each lane hit a row 4KB
// away, so one wave-load = 64 partial 64B-line transactions (4x amplified)
// -> ~860MB of L2/L3-granule traffic ~= L3 fabric ceiling. Vf[(b,c32,nt)]
// [lane] makes every PV load one dense contiguous 1KB wave-load.
// Fragment layouts (verified R2):
//   A[m][k]: m=lane&15, k=quad*8+j | B[k][n]: n=lane&15, k=quad*8+j
//   C/D:     col=lane&15, row=quad*4+reg
// PV B-frag for 32-key chunk c, dim-group nt: lane l holds
//   V[b][c*32 + (l>>4)*8 + j][nt*16 + (l&15)], j=0..7  (8 keys, 16B).

#define BATCH 8
#define SEQ 2048
#define DIM 64
#define NEL (BATCH * SEQ * DIM)

typedef __attribute__((ext_vector_type(8))) short short8;
typedef __attribute__((ext_vector_type(4))) float f32x4;

#define MFMA(a, b, c) __builtin_amdgcn_mfma_f32_16x16x32_bf16(a, b, c, 0, 0, 0)

__device__ __forceinline__ unsigned short f2bf(float x) {
    unsigned u = __float_as_uint(x);
    unsigned r = u + 0x7fffu + ((u >> 16) & 1u);   // RNE
    return (unsigned short)(r >> 16);
}
__device__ __forceinline__ float bf2f(unsigned short h) {
    return __uint_as_float(((unsigned)h) << 16);
}
__device__ __forceinline__ short8 ld8(const unsigned short* p) {
    return *(const short8*)p;
}

__device__ __forceinline__ float dpp_max16(float x) {
    float o;
    o = __int_as_float(__builtin_amdgcn_update_dpp(0, __float_as_int(x), 0xB1, 0xF, 0xF, true));
    x = fmaxf(x, o);
    o = __int_as_float(__builtin_amdgcn_update_dpp(0, __float_as_int(x), 0x4E, 0xF, 0xF, true));
    x = fmaxf(x, o);
    o = __int_as_float(__builtin_amdgcn_update_dpp(0, __float_as_int(x), 0x141, 0xF, 0xF, true));
    x = fmaxf(x, o);
    o = __int_as_float(__builtin_amdgcn_update_dpp(0, __float_as_int(x), 0x140, 0xF, 0xF, true));
    return fmaxf(x, o);
}
__device__ __forceinline__ float dpp_sum16(float x) {
    float o;
    o = __int_as_float(__builtin_amdgcn_update_dpp(0, __float_as_int(x), 0xB1, 0xF, 0xF, true));
    x += o;
    o = __int_as_float(__builtin_amdgcn_update_dpp(0, __float_as_int(x), 0x4E, 0xF, 0xF, true));
    x += o;
    o = __int_as_float(__builtin_amdgcn_update_dpp(0, __float_as_int(x), 0x141, 0xF, 0xF, true));
    x += o;
    o = __int_as_float(__builtin_amdgcn_update_dpp(0, __float_as_int(x), 0x140, 0xF, 0xF, true));
    return x + o;
}

// ---- pre-pass: Q/K hi-lo split convert + V fragment-major bf16 ----
__global__ __launch_bounds__(256) void prep(
    const float* __restrict__ Q, const float* __restrict__ K,
    const float* __restrict__ V,
    unsigned short* __restrict__ Qh, unsigned short* __restrict__ Ql,
    unsigned short* __restrict__ Kh, unsigned short* __restrict__ Kl,
    unsigned short* __restrict__ Vf)
{
    __shared__ unsigned short sT[64][72];   // [dim][key] for one 64-key tile
    const int blk = blockIdx.x;
    const int t = threadIdx.x;

    if (blk < 2048) {
        const int idx = (blk * 256 + t) * 4;
        const float* src; unsigned short *dh, *dl; int off;
        if (idx < NEL) { src = Q; dh = Qh; dl = Ql; off = idx; }
        else           { src = K; dh = Kh; dl = Kl; off = idx - NEL; }
        float4 v = *(const float4*)(src + off);
        ushort4 h, l;
        h.x = f2bf(v.x); l.x = f2bf(v.x - bf2f(h.x));
        h.y = f2bf(v.y); l.y = f2bf(v.y - bf2f(h.y));
        h.z = f2bf(v.z); l.z = f2bf(v.z - bf2f(h.z));
        h.w = f2bf(v.w); l.w = f2bf(v.w - bf2f(h.w));
        *(ushort4*)(dh + off) = h;
        *(ushort4*)(dl + off) = l;
        return;
    }

    const int tile = blk - 2048;            // 8 batches * 32 tiles of 64 keys
    const int b = tile >> 5;
    const int s0 = (tile & 31) * 64;
    const int srow = t >> 4;
    const int d4   = (t & 15) * 4;
#pragma unroll
    for (int i = 0; i < 4; ++i) {
        const int row = srow + i * 16;      // key within tile
        float4 v = *(const float4*)(V + ((size_t)(b * SEQ + s0 + row)) * DIM + d4);
        sT[d4 + 0][row] = f2bf(v.x);
        sT[d4 + 1][row] = f2bf(v.y);
        sT[d4 + 2][row] = f2bf(v.z);
        sT[d4 + 3][row] = f2bf(v.w);
    }
    __syncthreads();
    // write 2 chunks x 4 nt x 64 lanes fragments (16B each); 2 per thread
#pragma unroll
    for (int i = 0; i < 2; ++i) {
        const int fid = t + i * 256;        // 0..511
        const int cc  = fid >> 8;           // chunk within tile (0..1)
        const int nt  = (fid >> 6) & 3;     // dim group
        const int l   = fid & 63;           // lane
        const int key = cc * 32 + (l >> 4) * 8;
        const int dim = nt * 16 + (l & 15);
        const int c   = (s0 >> 5) + cc;     // global 32-key chunk (0..63)
        unsigned short* dst =
            Vf + ((((size_t)(b * 64 + c)) * 4 + nt) << 9) + l * 8;
        *(float4*)dst = *(const float4*)&sT[dim][key];
    }
}

// ---- main: 512 blocks x 256 threads (4 waves), q-tiles {pair, 127-pair} ----
__global__ __launch_bounds__(256) void attn_main(
    const unsigned short* __restrict__ Qh, const unsigned short* __restrict__ Ql,
    const unsigned short* __restrict__ Kh, const unsigned short* __restrict__ Kl,
    const unsigned short* __restrict__ Vf, float* __restrict__ O)
{
    // per-wave union scratch: sP (ushort[16][136]) == sO (float[16][68]) = 4352B
    __shared__ __align__(16) char scratch[4][4352];
    __shared__ float sMl[4][16][2];

    const int bid  = blockIdx.x;
    const int b    = bid & (BATCH - 1);
    const int pair = bid >> 3;              // 0..63

    const int t    = threadIdx.x;
    const int w    = t >> 6;
    const int lane = t & 63;
    const int quad = lane >> 4;
    const int n16  = lane & 15;
    const int boff = b * SEQ;

    unsigned short* sPw = (unsigned short*)scratch[w];   // [16][136]
    float*          sOw = (float*)scratch[w];            // [16][68]

    for (int half = 0; half < 2; ++half) {
        const int qt = half ? (127 - pair) : pair;
        const int q0 = qt * 16;
        const int q_max = q0 + 15;

        const unsigned short* qp  = Qh + ((size_t)(boff + q0 + n16)) * DIM + quad * 8;
        const unsigned short* qlp = Ql + ((size_t)(boff + q0 + n16)) * DIM + quad * 8;
        short8 qh0 = ld8(qp),  qh1 = ld8(qp + 32);
        short8 ql0 = ld8(qlp), ql1 = ld8(qlp + 32);

        float m0 = -1e30f, m1 = -1e30f, m2 = -1e30f, m3 = -1e30f;
        float l0 = 0.f, l1 = 0.f, l2 = 0.f, l3 = 0.f;
        f32x4 oacc[4];
#pragma unroll
        for (int i = 0; i < 4; ++i) oacc[i] = (f32x4){0.f, 0.f, 0.f, 0.f};

        for (int kb = w * 128; kb <= q_max; kb += 512) {
            const int rem  = q_max - kb;
            const int nsub = min(8, (rem >> 4) + 1);
            const int nchain = (nsub + 1) >> 1;
            f32x4 sacc[8];

            // ---- QK^T: 8 subtiles in pairs (16 loads in flight) ----
#pragma unroll
            for (int gp = 0; gp < 4; ++gp) {
                const int stA = 2 * gp, stB = stA + 1;
                if (stA < nsub) {
                    const size_t krA = (size_t)(boff + kb + stA * 16 + n16) * DIM + quad * 8;
                    short8 khA0 = ld8(Kh + krA), khA1 = ld8(Kh + krA + 32);
                    short8 klA0 = ld8(Kl + krA), klA1 = ld8(Kl + krA + 32);
                    const bool okB = (stB < nsub);
                    const size_t krB = (size_t)(boff + kb + stB * 16 + n16) * DIM + quad * 8;
                    short8 khB0, khB1, klB0, klB1;
                    if (okB) {
                        khB0 = ld8(Kh + krB); khB1 = ld8(Kh + krB + 32);
                        klB0 = ld8(Kl + krB); klB1 = ld8(Kl + krB + 32);
                    }
                    f32x4 accA = (f32x4){0.f, 0.f, 0.f, 0.f};
                    accA = MFMA(qh0, khA0, accA);
                    accA = MFMA(qh1, khA1, accA);
                    accA = MFMA(qh0, klA0, accA);
                    accA = MFMA(qh1, klA1, accA);
                    accA = MFMA(ql0, khA0, accA);
                    accA = MFMA(ql1, khA1, accA);
                    sacc[stA] = accA;
                    if (okB) {
                        f32x4 accB = (f32x4){0.f, 0.f, 0.f, 0.f};
                        accB = MFMA(qh0, khB0, accB);
                        accB = MFMA(qh1, khB1, accB);
                        accB = MFMA(qh0, klB0, accB);
                        accB = MFMA(qh1, klB1, accB);
                        accB = MFMA(ql0, khB0, accB);
                        accB = MFMA(ql1, khB1, accB);
                        sacc[stB] = accB;
                    } else {
                        sacc[stB] = (f32x4){-1e30f, -1e30f, -1e30f, -1e30f};
                    }
                } else {
                    sacc[stA] = (f32x4){-1e30f, -1e30f, -1e30f, -1e30f};
                    sacc[stB] = (f32x4){-1e30f, -1e30f, -1e30f, -1e30f};
                }
            }

            // ---- causal mask: any chunk overlapping any query row ----
            if (kb + 127 > q0) {
#pragma unroll
                for (int st = 0; st < 8; ++st) {
                    if (st < nsub) {
                        const int key = kb + st * 16 + n16;
#pragma unroll
                        for (int r = 0; r < 4; ++r)
                            if (key > q0 + quad * 4 + r) sacc[st][r] = -1e30f;
                    }
                }
            }

            // ---- online softmax over 128 keys (DPP reductions) ----
            float mt0 = sacc[0][0], mt1 = sacc[0][1], mt2 = sacc[0][2], mt3 = sacc[0][3];
#pragma unroll
            for (int st = 1; st < 8; ++st) {
                mt0 = fmaxf(mt0, sacc[st][0]);
                mt1 = fmaxf(mt1, sacc[st][1]);
                mt2 = fmaxf(mt2, sacc[st][2]);
                mt3 = fmaxf(mt3, sacc[st][3]);
            }
            mt0 = dpp_max16(mt0); mt1 = dpp_max16(mt1);
            mt2 = dpp_max16(mt2); mt3 = dpp_max16(mt3);
            const float mn0 = fmaxf(m0, mt0), mn1 = fmaxf(m1, mt1);
            const float mn2 = fmaxf(m2, mt2), mn3 = fmaxf(m3, mt3);
            const float a0 = __expf(m0 - mn0), a1 = __expf(m1 - mn1);
            const float a2 = __expf(m2 - mn2), a3 = __expf(m3 - mn3);
            m0 = mn0; m1 = mn1; m2 = mn2; m3 = mn3;

            float ps0 = 0.f, ps1 = 0.f, ps2 = 0.f, ps3 = 0.f;
            const int stmax = 2 * nchain;
#pragma unroll
            for (int st = 0; st < 8; ++st) {
                if (st < stmax) {
                    float p0 = 0.f, p1 = 0.f, p2 = 0.f, p3 = 0.f;
                    if (st < nsub) {
                        p0 = __expf(sacc[st][0] - mn0);
                        p1 = __expf(sacc[st][1] - mn1);
                        p2 = __expf(sacc[st][2] - mn2);
                        p3 = __expf(sacc[st][3] - mn3);
                        ps0 += p0; ps1 += p1; ps2 += p2; ps3 += p3;
                    }
                    const int col = st * 16 + n16;
                    sPw[(quad * 4 + 0) * 136 + col] = f2bf(p0);
                    sPw[(quad * 4 + 1) * 136 + col] = f2bf(p1);
                    sPw[(quad * 4 + 2) * 136 + col] = f2bf(p2);
                    sPw[(quad * 4 + 3) * 136 + col] = f2bf(p3);
                }
            }
            ps0 = dpp_sum16(ps0); ps1 = dpp_sum16(ps1);
            ps2 = dpp_sum16(ps2); ps3 = dpp_sum16(ps3);
            l0 = l0 * a0 + ps0; l1 = l1 * a1 + ps1;
            l2 = l2 * a2 + ps2; l3 = l3 * a3 + ps3;
#pragma unroll
            for (int nt = 0; nt < 4; ++nt) {
                oacc[nt][0] *= a0; oacc[nt][1] *= a1;
                oacc[nt][2] *= a2; oacc[nt][3] *= a3;
            }

            // ---- PV: P from same-wave LDS; V via dense fragment-major loads ----
#pragma unroll
            for (int ch = 0; ch < 4; ++ch) {
                if (ch < nchain) {
                    short8 pa = ld8(&sPw[n16 * 136 + ch * 32 + quad * 8]);
                    const size_t cbase =
                        (((size_t)(b * 64 + (kb >> 5) + ch)) * 4) << 9;
#pragma unroll
                    for (int nt = 0; nt < 4; ++nt) {
                        short8 vv = ld8(Vf + cbase + (nt << 9) + lane * 8);
                        oacc[nt] = MFMA(pa, vv, oacc[nt]);
                    }
                }
            }
        }

        // ---- flash-combine the 4 waves' partials (sO overlays sP) ----
#pragma unroll
        for (int nt = 0; nt < 4; ++nt)
#pragma unroll
            for (int r = 0; r < 4; ++r)
                sOw[(quad * 4 + r) * 68 + nt * 16 + n16] = oacc[nt][r];
        if (n16 == 0) {
            sMl[w][quad * 4 + 0][0] = m0; sMl[w][quad * 4 + 0][1] = l0;
            sMl[w][quad * 4 + 1][0] = m1; sMl[w][quad * 4 + 1][1] = l1;
            sMl[w][quad * 4 + 2][0] = m2; sMl[w][quad * 4 + 2][1] = l2;
            sMl[w][quad * 4 + 3][0] = m3; sMl[w][quad * 4 + 3][1] = l3;
        }
        __syncthreads();

        const int row  = t >> 4;
        const int col4 = (t & 15) * 4;
        float M = fmaxf(fmaxf(sMl[0][row][0], sMl[1][row][0]),
                        fmaxf(sMl[2][row][0], sMl[3][row][0]));
        float L = 0.f;
        float ox = 0.f, oy = 0.f, oz = 0.f, ow = 0.f;
#pragma unroll
        for (int wv = 0; wv < 4; ++wv) {
            const float ew = __expf(sMl[wv][row][0] - M);
            L += ew * sMl[wv][row][1];
            const float* op = (const float*)scratch[wv] + row * 68 + col4;
            ox += ew * op[0]; oy += ew * op[1]; oz += ew * op[2]; ow += ew * op[3];
        }
        const float inv = 1.0f / L;
        float4 res = make_float4(ox * inv, oy * inv, oz * inv, ow * inv);
        *(float4*)(O + ((size_t)(boff + q0 + row)) * DIM + col4) = res;

        __syncthreads();   // scratch reused as sP by the next half
    }
}

extern "C" void kernel_launch(void* const* d_in, const int* in_sizes, int n_in,
                              void* d_out, int out_size, void* d_ws, size_t ws_size,
                              hipStream_t stream) {
    const float* q = (const float*)d_in[0];
    const float* k = (const float*)d_in[1];
    const float* v = (const float*)d_in[2];
    float* out = (float*)d_out;

    unsigned short* Qh = (unsigned short*)d_ws;
    unsigned short* Ql = Qh + NEL;
    unsigned short* Kh = Ql + NEL;
    unsigned short* Kl = Kh + NEL;
    unsigned short* Vf = Kl + NEL;   // 10 MB total in d_ws

    prep<<<dim3(2048 + 256), dim3(256), 0, stream>>>(q, k, v, Qh, Ql, Kh, Kl, Vf);
    attn_main<<<dim3(512), dim3(256), 0, stream>>>(Qh, Ql, Kh, Kl, Vf, out);
}